// Round 9
// baseline (250.588 us; speedup 1.0000x reference)
//
#include <hip/hip_runtime.h>

typedef __bf16 bf16x8 __attribute__((ext_vector_type(8)));
typedef float  f32x4  __attribute__((ext_vector_type(4)));
typedef unsigned short u16x8 __attribute__((ext_vector_type(8)));
typedef unsigned short u16x4 __attribute__((ext_vector_type(4)));

// Problem constants
constexpr int BB    = 16;
constexpr int TT    = 12;
constexpr int NN    = 307;
constexpr int TN    = TT * NN;        // 3684
constexpr int ROWSX = BB * TT * NN;   // 58944
constexpr int ROWSH = BB * NN;        // 4912
constexpr int SST1  = 3712;           // sag row stride (464 x b128 chunks)
constexpr int SSTR  = 3840;           // xnT row stride
constexpr int HPS   = ROWSH * 64;     // hp slab stride (314368 floats)
constexpr int KQ    = 928;            // pv K-split chunk (3712/4)
constexpr int WBS   = 264;            // score LDS u16 stride (132 dw = 4 mod 32 -> 2-way)
constexpr int SCORE_VB = 15 * 10 * BB; // 256j x 32n tiles: 15 x 10 x 16 = 2400
constexpr float SCALE = 0.125f;

__device__ __forceinline__ float wred_sum(float v) {
#pragma unroll
    for (int m = 32; m > 0; m >>= 1) v += __shfl_xor(v, m, 64);
    return v;
}

// ---------------------------------------------------------------------------
// prep_k: grid-specialized merge of fold (16 blk) + wconv (128 blk) + ln
// (14736 blk). All three depend only on kernel inputs.
// ---------------------------------------------------------------------------
__global__ __launch_bounds__(256) void prep_k(const float* __restrict__ qw,
                                              const float* __restrict__ qb,
                                              const float* __restrict__ kw,
                                              const float* __restrict__ kb,
                                              const float* __restrict__ fc1w,
                                              const float* __restrict__ fc2w,
                                              const float* __restrict__ x,
                                              const float* __restrict__ g,
                                              const float* __restrict__ b,
                                              float* __restrict__ M,
                                              float* __restrict__ b2,
                                              float* __restrict__ vv,
                                              float* __restrict__ cc,
                                              __bf16* __restrict__ fc1b16,
                                              __bf16* __restrict__ fc2b16,
                                              __bf16* __restrict__ xnb,
                                              float* __restrict__ y32) {
    int bx = blockIdx.x, t = threadIdx.x;
    int w = t >> 6, lane = t & 63;
    if (bx < 16) {
        // ---- fold: dg = q.k = qt.x_ + c ----
        int e = bx * 4 + w, d = lane;
        float acc = 0.f;
        for (int dp = 0; dp < 64; ++dp) acc += qw[dp * 64 + e] * kw[dp * 64 + d];
        M[e * 64 + d] = acc;
        float vp = wred_sum(qw[d * 64 + e] * kb[d]);
        if (lane == 0) vv[e] = vp;
        if (e == 0) {
            float bv = 0.f;
            for (int dp = 0; dp < 64; ++dp) bv += qb[dp] * kw[dp * 64 + d];
            b2[d] = bv;
            float cp = wred_sum(qb[d] * kb[d]);
            if (d == 0) *cc = cp;
        }
    } else if (bx < 144) {
        // ---- wconv: fc1w/fc2w fp32 -> bf16 ----
        int i = (bx - 16) * 256 + t;
        if (i < 16384) fc1b16[i] = (__bf16)fc1w[i];
        else fc2b16[i - 16384] = (__bf16)fc2w[i - 16384];
    } else {
        // ---- ln: 1 row/wave ----
        int r = (bx - 144) * 4 + w;
        if (r >= ROWSX) return;
        float val = x[r * 64 + lane];
        float mu  = wred_sum(val) * (1.f / 64.f);
        float dv  = val - mu;
        float var = wred_sum(dv * dv) * (1.f / 64.f);
        float xv  = dv * rsqrtf(var + 1e-5f) * g[lane] + b[lane];
        xnb[(size_t)r * 64 + lane] = (__bf16)xv;
        int tt = (r / NN) % TT;
        if (tt == TT - 1) {
            int bbv = r / (NN * TT), n = r % NN;
            y32[(bbv * NN + n) * 64 + lane] = xv;
        }
    }
}

// ---------------------------------------------------------------------------
// qt[row] = y_ @ M + b2 (bf16);  cq[row] = y_.v + cc
// ---------------------------------------------------------------------------
__global__ __launch_bounds__(256) void qt_k(const float* __restrict__ y32,
                                            const float* __restrict__ M,
                                            const float* __restrict__ b2,
                                            const float* __restrict__ vv,
                                            const float* __restrict__ ccp,
                                            __bf16* __restrict__ qtb,
                                            float* __restrict__ cq) {
    int w = threadIdx.x >> 6, l = threadIdx.x & 63;
    int rr = blockIdx.x * 4 + w;
    if (rr >= ROWSH) return;
    float y = y32[rr * 64 + l];
    float acc = b2[l];
#pragma unroll
    for (int e = 0; e < 64; ++e) acc += __shfl(y, e, 64) * M[e * 64 + l];
    qtb[(size_t)rr * 64 + l] = (__bf16)acc;
    float cp = wred_sum(y * vv[l]);
    if (l == 0) cq[rr] = cp + *ccp;
}

// ---------------------------------------------------------------------------
// score_k v6: 32n x 256j tiles, blocked-jt (wave w owns jt=4w..4w+3).
// R8 post-mortem: 2x occupancy did NOT help (DRAM-gather-bound, 2.5 TB/s) ->
// keep R7's register/occupancy config, lengthen DRAM runs instead: per wave
// per nt the stg read is 16 rows x 256B contiguous (was 128B) and a block
// touches 32 rows (was 64) -> half the page spread, 2x run length. sag
// store chunks also 2x (512B/row). Store guard for the 3712-stride tail.
// t-rider unchanged (vb >= SCORE_VB).
// ---------------------------------------------------------------------------
__global__ __launch_bounds__(256, 4) void score_k(const __bf16* __restrict__ qtb,
                                                  const float* __restrict__ cq,
                                                  const __bf16* __restrict__ xnb,
                                                  const float* __restrict__ stg,
                                                  __bf16* __restrict__ sag,
                                                  __bf16* __restrict__ xnT) {
    __shared__ unsigned short wb[32 * WBS];   // 16.5 KB (score) / 8.3 KB (t)
    int vb = blockIdx.x;
    int t = threadIdx.x;

    if (vb >= SCORE_VB) {
        // ---- transpose rider: xnb[b,j,d] -> xnT[b,d,j] ----
        int u = vb - SCORE_VB;
        int bb = u / 58, j0 = (u % 58) * 64;
        unsigned short (*tile)[65] = (unsigned short(*)[65])wb;
        const unsigned short* src = (const unsigned short*)xnb;
        unsigned short* dst = (unsigned short*)xnT;
#pragma unroll
        for (int i = 0; i < 16; ++i) {
            int f = t + 256 * i, jr = f >> 6, dc = f & 63;
            int j = j0 + jr;
            tile[jr][dc] = (j < TN) ? src[((size_t)bb * TN + j) * 64 + dc] : (unsigned short)0;
        }
        __syncthreads();
#pragma unroll
        for (int i = 0; i < 16; ++i) {
            int f = t + 256 * i, d = f >> 6, jj = f & 63;
            dst[((size_t)bb * 64 + d) * SSTR + j0 + jj] = tile[jj][d];
        }
        return;
    }

    int jb = vb % 15, nb = (vb / 15) % 10, bb = vb / 150;
    int n0 = nb * 32, j0 = jb * 256;
    int w = t >> 6, lane = t & 63;
    int m16 = lane & 15, q4 = lane >> 4;

    // ---- prefetch stg (8 x float4, 256B runs per row) + cq (2) ----
    const float* stgb = stg + (size_t)bb * NN * TN;
    float4 sv[2][4];
    float cn[2];
#pragma unroll
    for (int nt = 0; nt < 2; ++nt) {
        int n = n0 + nt * 16 + m16;
        const float* srow = stgb + (size_t)min(n, NN - 1) * TN;
#pragma unroll
        for (int jtl = 0; jtl < 4; ++jtl) {
            int jc = j0 + (w * 4 + jtl) * 16 + q4 * 4;   // 4-aligned; TN is 4-aligned
            float4 s4 = {0.f, 0.f, 0.f, 0.f};
            if (jc < TN) s4 = *(const float4*)(srow + jc);
            sv[nt][jtl] = s4;
        }
        cn[nt] = (n < NN) ? cq[bb * NN + n] : 0.f;
    }

    // ---- A fragments: xnb rows j (wave w owns jt = 4w..4w+3) ----
    bf16x8 a[4][2];
#pragma unroll
    for (int jtl = 0; jtl < 4; ++jtl) {
        const bf16x8* ap = (const bf16x8*)(xnb + ((size_t)bb * TN + j0 + (w * 4 + jtl) * 16 + m16) * 64);
        a[jtl][0] = ap[q4];
        a[jtl][1] = ap[q4 + 4];
    }

    // ---- MFMA: C[j_local][n_local], 4 jtl x 2 nt tiles per wave ----
    f32x4 acc[4][2];
#pragma unroll
    for (int nt = 0; nt < 2; ++nt) {
        const bf16x8* bp = (const bf16x8*)(qtb + ((size_t)bb * NN + n0 + nt * 16 + m16) * 64);
        bf16x8 b0 = bp[q4], b1 = bp[q4 + 4];
#pragma unroll
        for (int jtl = 0; jtl < 4; ++jtl) {
            f32x4 c = {0.f, 0.f, 0.f, 0.f};
            c = __builtin_amdgcn_mfma_f32_16x16x32_bf16(a[jtl][0], b0, c, 0, 0, 0);
            c = __builtin_amdgcn_mfma_f32_16x16x32_bf16(a[jtl][1], b1, c, 0, 0, 0);
            acc[jtl][nt] = c;
        }
    }

    // ---- epilogue: sigmoid(dg)*stg*scale from registers only ----
#pragma unroll
    for (int nt = 0; nt < 2; ++nt) {
#pragma unroll
        for (int jtl = 0; jtl < 4; ++jtl) {
            int jc = j0 + (w * 4 + jtl) * 16 + q4 * 4;
            float svv[4] = {sv[nt][jtl].x, sv[nt][jtl].y, sv[nt][jtl].z, sv[nt][jtl].w};
            u16x4 hw;
#pragma unroll
            for (int r = 0; r < 4; ++r) {
                float dg = (acc[jtl][nt][r] + cn[nt]) * SCALE;
                float s  = 1.f / (1.f + __expf(-dg));
                float wv = (jc + r < TN) ? s * svv[r] * SCALE : 0.f;
                __bf16 wb16 = (__bf16)wv;
                hw[r] = *(unsigned short*)&wb16;
            }
            *(u16x4*)&wb[(nt * 16 + m16) * WBS + (w * 4 + jtl) * 16 + q4 * 4] = hw;
        }
    }
    __syncthreads();

    // ---- coalesced b128 stores (1024 chunks, 4/thread, 512B runs/row) ----
#pragma unroll
    for (int i = 0; i < 4; ++i) {
        int chunk = t + i * 256;          // 0..1023
        int row = chunk >> 5, c8 = (chunk & 31) * 8;
        int n = n0 + row;
        int j = j0 + c8;
        if (n < NN && j < SST1) {
            u16x8 v = *(const u16x8*)&wb[row * WBS + c8];
            *(u16x8*)((unsigned short*)sag + (size_t)(bb * NN + n) * SST1 + j) = v;
        }
    }
}

// ---------------------------------------------------------------------------
// Softmax+topk, one wave per row, zero LDS. Writes UNnormalized exp weights
// in place + per-row sum to rsum[]; pv divides in its epilogue.
// ---------------------------------------------------------------------------
__global__ __launch_bounds__(256) void smax_k(__bf16* __restrict__ sagB,
                                              const int* __restrict__ topk_p,
                                              float* __restrict__ rsum) {
    int t = threadIdx.x;
    int wid = t >> 6, lane = t & 63;
    int row = blockIdx.x * 4 + wid;
    if (row >= ROWSH) return;

    int topkv = *topk_p;
    bool selAll = (topkv <= 0);
    int kk = 0;
    if (!selAll) {
        kk = (topkv < 5) ? topkv * NN : topkv;
        if (kk > TN) kk = TN;
    }

    u16x8* src = (u16x8*)((unsigned short*)sagB + (size_t)row * SST1);
    u16x8 va[8];
#pragma unroll
    for (int ci = 0; ci < 8; ++ci) {
        int c = lane + (ci << 6);
        u16x8 v = {0, 0, 0, 0, 0, 0, 0, 0};
        if (c < 464) v = src[c];
        va[ci] = v;
    }
    // row max (values >= 0; bf16 bit order = value order; pads 0)
    int vmb = 0;
#pragma unroll
    for (int ci = 0; ci < 8; ++ci)
#pragma unroll
        for (int e = 0; e < 8; ++e) vmb = max(vmb, (int)va[ci][e]);
#pragma unroll
    for (int m = 32; m > 0; m >>= 1) vmb = max(vmb, __shfl_xor(vmb, m, 64));
    float vmax = __uint_as_float(((unsigned)vmb) << 16);

    // exact kk-th largest: smallest T with cnt(>T) < kk (ballot+popcount)
    unsigned thrb = 0;
    if (!selAll) {
        unsigned lo = 0, hi = (unsigned)vmb;
        while (lo < hi) {
            unsigned mid = (lo + hi) >> 1;
            int cnt = 0;
#pragma unroll
            for (int ci = 0; ci < 8; ++ci)
#pragma unroll
                for (int e = 0; e < 8; ++e)
                    cnt += (int)__popcll(__ballot((unsigned)va[ci][e] > mid));
            if (cnt < kk) hi = mid; else lo = mid + 1;
        }
        thrb = lo;
    }

    // exp over selected (store unnormalized exp as bf16)
    float local = 0.f;
#pragma unroll
    for (int ci = 0; ci < 8; ++ci) {
        int c = lane + (ci << 6);
        int nvv = (c < 460) ? 8 : ((c == 460) ? 4 : 0);
#pragma unroll
        for (int e = 0; e < 8; ++e) {
            unsigned u = va[ci][e];
            bool sel = selAll ? (e < nvv) : (u > thrb);
            float ev = sel ? __expf(__uint_as_float(u << 16) - vmax) : 0.f;
            local += ev;
            __bf16 eb = (__bf16)ev;
            va[ci][e] = *(unsigned short*)&eb;
        }
    }
    local = wred_sum(local);
    bool uni = !(local > 0.f);
    if (lane == 0) rsum[row] = uni ? (float)TN : local;

    if (uni) {
        __bf16 one = (__bf16)1.f, zero = (__bf16)0.f;
#pragma unroll
        for (int ci = 0; ci < 8; ++ci) {
            int c = lane + (ci << 6);
            if (c < 464) {
                int nvv = (c < 460) ? 8 : ((c == 460) ? 4 : 0);
                bf16x8 o;
#pragma unroll
                for (int e = 0; e < 8; ++e) o[e] = (e < nvv) ? one : zero;
                *(bf16x8*)&src[c] = o;
            }
        }
    } else {
#pragma unroll
        for (int ci = 0; ci < 8; ++ci) {
            int c = lane + (ci << 6);
            if (c < 464) src[c] = va[ci];
        }
    }
}

// ---------------------------------------------------------------------------
// PV GEMM, K-split 4 across blocks, XCD-swizzled (1280 = 8x160, bijective):
// all 20 n-blocks sharing one (bb,kq) xnT panel land on one XCD's L2.
// ---------------------------------------------------------------------------
__global__ __launch_bounds__(256) void pv_k(const __bf16* __restrict__ sagB,
                                            const __bf16* __restrict__ xnT,
                                            const float* __restrict__ y32,
                                            const float* __restrict__ rsum,
                                            float* __restrict__ hp) {
    int p = blockIdx.x + 20 * (blockIdx.y + 4 * blockIdx.z);   // 0..1279
    int l = (p & 7) * 160 + (p >> 3);
    int n0 = (l % 20) * 16;
    int kq = (l / 20) & 3;
    int bb = l / 80;
    int wid = threadIdx.x >> 6, lane = threadIdx.x & 63;
    int m16 = lane & 15, q4 = lane >> 4;

    int arow = min(n0 + m16, NN - 1);   // clamp: garbage rows masked at store
    const __bf16* ab  = sagB + (size_t)(bb * NN + arow) * SST1 + kq * KQ + q4 * 8;
    const __bf16* bbp = xnT + ((size_t)bb * 64 + wid * 16 + m16) * SSTR + kq * KQ + q4 * 8;

    f32x4 acc0 = {0.f, 0.f, 0.f, 0.f}, acc1 = {0.f, 0.f, 0.f, 0.f};
#pragma unroll 4
    for (int ks = 0; ks < 29; ++ks) {               // 29 * K32 = 928
        bf16x8 a = *(const bf16x8*)(ab + ks * 32);
        bf16x8 b = *(const bf16x8*)(bbp + ks * 32);
        if (ks & 1) acc1 = __builtin_amdgcn_mfma_f32_16x16x32_bf16(a, b, acc1, 0, 0, 0);
        else        acc0 = __builtin_amdgcn_mfma_f32_16x16x32_bf16(a, b, acc0, 0, 0, 0);
    }
    // C layout: row = q4*4+r (A-row = n), col = m16 (B-row = d within tile)
#pragma unroll
    for (int r = 0; r < 4; ++r) {
        int n = n0 + q4 * 4 + r;
        if (n < NN) {
            size_t o = (size_t)(bb * NN + n) * 64 + wid * 16 + m16;
            float inv = 1.f / rsum[bb * NN + n];
            float v = (acc0[r] + acc1[r]) * inv;
            if (kq == 0) v += y32[o];
            hp[(size_t)kq * HPS + o] = v;
        }
    }
}

// ---------------------------------------------------------------------------
// FFN via MFMA bf16: h = sum(hp[0..3]) -> LN -> @fc1^T+relu -> @fc2^T + h + b.
// hsum stashed in LDS during the LN pass.
// ---------------------------------------------------------------------------
__global__ __launch_bounds__(256) void ffn_k(const float* __restrict__ hp,
                                             const float* __restrict__ g,
                                             const float* __restrict__ bln,
                                             const __bf16* __restrict__ fc1b16,
                                             const float* __restrict__ fc1b,
                                             const __bf16* __restrict__ fc2b16,
                                             const float* __restrict__ fc2b,
                                             float* __restrict__ out) {
    __shared__ __bf16 zb[16 * 68];
    __shared__ __bf16 ab[16 * 264];
    __shared__ float hs[16][66];
    int t = threadIdx.x, r0 = blockIdx.x * 16;
    int wid = t >> 6, lane = t & 63;
    int m16 = lane & 15, q4 = lane >> 4;

#pragma unroll
    for (int q = 0; q < 4; ++q) {
        int rl = wid * 4 + q;
        size_t i = (size_t)(r0 + rl) * 64 + lane;
        float val = hp[i] + hp[HPS + i] + hp[2 * HPS + i] + hp[3 * HPS + i];
        hs[rl][lane] = val;
        float mu  = wred_sum(val) * (1.f / 64.f);
        float dv  = val - mu;
        float var = wred_sum(dv * dv) * (1.f / 64.f);
        zb[rl * 68 + lane] = (__bf16)(dv * rsqrtf(var + 1e-5f) * g[lane] + bln[lane]);
    }
    __syncthreads();

    bf16x8 a0 = *(const bf16x8*)&zb[m16 * 68 + q4 * 8];
    bf16x8 a1 = *(const bf16x8*)&zb[m16 * 68 + 32 + q4 * 8];
#pragma unroll
    for (int jt2 = 0; jt2 < 4; ++jt2) {
        int j0t = (wid * 4 + jt2) * 16;
        const __bf16* bp = fc1b16 + (size_t)(j0t + m16) * 64 + q4 * 8;
        f32x4 c = {0.f, 0.f, 0.f, 0.f};
        c = __builtin_amdgcn_mfma_f32_16x16x32_bf16(a0, *(const bf16x8*)bp, c, 0, 0, 0);
        c = __builtin_amdgcn_mfma_f32_16x16x32_bf16(a1, *(const bf16x8*)(bp + 32), c, 0, 0, 0);
        int j = j0t + m16;
        float bias = fc1b[j];
#pragma unroll
        for (int r = 0; r < 4; ++r)
            ab[(q4 * 4 + r) * 264 + j] = (__bf16)fmaxf(c[r] + bias, 0.f);
    }
    __syncthreads();

    f32x4 c2a = {0.f, 0.f, 0.f, 0.f}, c2b = {0.f, 0.f, 0.f, 0.f};
    const __bf16* b2p = fc2b16 + (size_t)(wid * 16 + m16) * 256 + q4 * 8;
#pragma unroll
    for (int k8 = 0; k8 < 8; k8 += 2) {
        bf16x8 aa0 = *(const bf16x8*)&ab[m16 * 264 + k8 * 32 + q4 * 8];
        bf16x8 aa1 = *(const bf16x8*)&ab[m16 * 264 + (k8 + 1) * 32 + q4 * 8];
        c2a = __builtin_amdgcn_mfma_f32_16x16x32_bf16(aa0, *(const bf16x8*)(b2p + k8 * 32), c2a, 0, 0, 0);
        c2b = __builtin_amdgcn_mfma_f32_16x16x32_bf16(aa1, *(const bf16x8*)(b2p + (k8 + 1) * 32), c2b, 0, 0, 0);
    }
    int d = wid * 16 + m16;
    float bias2 = fc2b[d];
#pragma unroll
    for (int r = 0; r < 4; ++r) {
        size_t row = (size_t)(r0 + q4 * 4 + r);
        size_t o = row * 64 + d;
        out[o] = hs[q4 * 4 + r][d] + c2a[r] + c2b[r] + bias2;
    }
}

extern "C" void kernel_launch(void* const* d_in, const int* in_sizes, int n_in,
                              void* d_out, int out_size, void* d_ws, size_t ws_size,
                              hipStream_t stream) {
    const float* x    = (const float*)d_in[0];
    const float* stg  = (const float*)d_in[1];
    const int*   topk = (const int*)d_in[2];
    const float* qw   = (const float*)d_in[3];
    const float* qb   = (const float*)d_in[4];
    const float* kw   = (const float*)d_in[5];
    const float* kb   = (const float*)d_in[6];
    const float* lng  = (const float*)d_in[7];
    const float* lnb  = (const float*)d_in[8];
    const float* flng = (const float*)d_in[9];
    const float* flnb = (const float*)d_in[10];
    const float* fc1w = (const float*)d_in[11];
    const float* fc1b = (const float*)d_in[12];
    const float* fc2w = (const float*)d_in[13];
    const float* fc2b = (const float*)d_in[14];
    float* out = (float*)d_out;

    float* ws = (float*)d_ws;
    __bf16* xnb = (__bf16*)ws;                 // ROWSX*64 bf16 = 1,886,208 f
    float* p1   = ws + 1886208;
    __bf16* xnT = (__bf16*)p1;                 // 16*64*3840 bf16 = 1,966,080 f
    float* p2   = p1 + 1966080;
    __bf16* qtb = (__bf16*)p2;                 // 4928*64 bf16 = 157,696 f
    float* y32  = p2 + 157696;                 // 314,368 f
    float* cq   = y32 + 314368;                // 4,928 f
    float* M    = cq + 4928;                   // 4,096
    float* b2   = M + 4096;                    // 64
    float* vv   = b2 + 64;                     // 64
    float* cc   = vv + 64;                     // 16
    __bf16* fc1b16 = (__bf16*)(cc + 16);       // 8,192 f
    __bf16* fc2b16 = (__bf16*)((float*)fc1b16 + 8192);  // 8,192 f
    __bf16* sag = (__bf16*)((float*)fc2b16 + 8192);     // ROWSH*3712 bf16 = 9,116,672 f
    float* hp   = (float*)sag + 9116672;       // 4*314,368 f (K-split partials)
    float* rsum = hp + 4 * HPS;                // 4,928 f

    prep_k<<<144 + (ROWSX + 3) / 4, 256, 0, stream>>>(qw, qb, kw, kb, fc1w, fc2w,
                                                      x, lng, lnb,
                                                      M, b2, vv, cc,
                                                      fc1b16, fc2b16, xnb, y32);
    qt_k<<<(ROWSH + 3) / 4, 256, 0, stream>>>(y32, M, b2, vv, cc, qtb, cq);
    score_k<<<SCORE_VB + 58 * BB, 256, 0, stream>>>(qtb, cq, xnb, stg, sag, xnT);
    smax_k<<<(ROWSH + 3) / 4, 256, 0, stream>>>(sag, topk, rsum);
    pv_k<<<dim3((NN + 15) / 16, 4, BB), 256, 0, stream>>>(sag, xnT, y32, rsum, hp);
    ffn_k<<<ROWSH / 16, 256, 0, stream>>>(hp, flng, flnb, fc1b16, fc1b, fc2b16, fc2b, out);
}

// Round 11
// 250.230 us; speedup vs baseline: 1.0014x; 1.0014x over previous
//
#include <hip/hip_runtime.h>

typedef __bf16 bf16x8 __attribute__((ext_vector_type(8)));
typedef float  f32x4  __attribute__((ext_vector_type(4)));
typedef unsigned short u16x8 __attribute__((ext_vector_type(8)));
typedef unsigned short u16x4 __attribute__((ext_vector_type(4)));

// Problem constants
constexpr int BB    = 16;
constexpr int TT    = 12;
constexpr int NN    = 307;
constexpr int TN    = TT * NN;        // 3684
constexpr int ROWSX = BB * TT * NN;   // 58944
constexpr int ROWSH = BB * NN;        // 4912
constexpr int SST1  = 3712;           // sag row stride (464 x b128 chunks)
constexpr int SSTR  = 3840;           // xnT row stride
constexpr int HPS   = ROWSH * 64;     // hp slab stride (314368 floats)
constexpr int KQ    = 928;            // pv K-split chunk (3712/4)
constexpr int WBS   = 152;            // score LDS stride: 76 dw = 12 mod 32 -> 2-way max
constexpr int SCORE_VB = 145 * BB;    // 29 j-blk x 5 n-blk x 16 = 2320
constexpr float SCALE = 0.125f;

__device__ __forceinline__ float wred_sum(float v) {
#pragma unroll
    for (int m = 32; m > 0; m >>= 1) v += __shfl_xor(v, m, 64);
    return v;
}

// ---------------------------------------------------------------------------
// prep_k: grid-specialized merge of fold (16 blk) + wconv (128 blk) + ln
// (14736 blk). All three depend only on kernel inputs.
// ---------------------------------------------------------------------------
__global__ __launch_bounds__(256) void prep_k(const float* __restrict__ qw,
                                              const float* __restrict__ qb,
                                              const float* __restrict__ kw,
                                              const float* __restrict__ kb,
                                              const float* __restrict__ fc1w,
                                              const float* __restrict__ fc2w,
                                              const float* __restrict__ x,
                                              const float* __restrict__ g,
                                              const float* __restrict__ b,
                                              float* __restrict__ M,
                                              float* __restrict__ b2,
                                              float* __restrict__ vv,
                                              float* __restrict__ cc,
                                              __bf16* __restrict__ fc1b16,
                                              __bf16* __restrict__ fc2b16,
                                              __bf16* __restrict__ xnb,
                                              float* __restrict__ y32) {
    int bx = blockIdx.x, t = threadIdx.x;
    int w = t >> 6, lane = t & 63;
    if (bx < 16) {
        // ---- fold: dg = q.k = qt.x_ + c ----
        int e = bx * 4 + w, d = lane;
        float acc = 0.f;
        for (int dp = 0; dp < 64; ++dp) acc += qw[dp * 64 + e] * kw[dp * 64 + d];
        M[e * 64 + d] = acc;
        float vp = wred_sum(qw[d * 64 + e] * kb[d]);
        if (lane == 0) vv[e] = vp;
        if (e == 0) {
            float bv = 0.f;
            for (int dp = 0; dp < 64; ++dp) bv += qb[dp] * kw[dp * 64 + d];
            b2[d] = bv;
            float cp = wred_sum(qb[d] * kb[d]);
            if (d == 0) *cc = cp;
        }
    } else if (bx < 144) {
        // ---- wconv: fc1w/fc2w fp32 -> bf16 ----
        int i = (bx - 16) * 256 + t;
        if (i < 16384) fc1b16[i] = (__bf16)fc1w[i];
        else fc2b16[i - 16384] = (__bf16)fc2w[i - 16384];
    } else {
        // ---- ln: 1 row/wave ----
        int r = (bx - 144) * 4 + w;
        if (r >= ROWSX) return;
        float val = x[r * 64 + lane];
        float mu  = wred_sum(val) * (1.f / 64.f);
        float dv  = val - mu;
        float var = wred_sum(dv * dv) * (1.f / 64.f);
        float xv  = dv * rsqrtf(var + 1e-5f) * g[lane] + b[lane];
        xnb[(size_t)r * 64 + lane] = (__bf16)xv;
        int tt = (r / NN) % TT;
        if (tt == TT - 1) {
            int bbv = r / (NN * TT), n = r % NN;
            y32[(bbv * NN + n) * 64 + lane] = xv;
        }
    }
}

// ---------------------------------------------------------------------------
// qt[row] = y_ @ M + b2 (bf16);  cq[row] = y_.v + cc
// ---------------------------------------------------------------------------
__global__ __launch_bounds__(256) void qt_k(const float* __restrict__ y32,
                                            const float* __restrict__ M,
                                            const float* __restrict__ b2,
                                            const float* __restrict__ vv,
                                            const float* __restrict__ ccp,
                                            __bf16* __restrict__ qtb,
                                            float* __restrict__ cq) {
    int w = threadIdx.x >> 6, l = threadIdx.x & 63;
    int rr = blockIdx.x * 4 + w;
    if (rr >= ROWSH) return;
    float y = y32[rr * 64 + l];
    float acc = b2[l];
#pragma unroll
    for (int e = 0; e < 64; ++e) acc += __shfl(y, e, 64) * M[e * 64 + l];
    qtb[(size_t)rr * 64 + l] = (__bf16)acc;
    float cp = wred_sum(y * vv[l]);
    if (l == 0) cq[rr] = cp + *ccp;
}

// ---------------------------------------------------------------------------
// score_k (R7 config — best measured; R8 occupancy-2x and R9 tile-reshape
// both regressed). 64n x 128j tiles, register-prefetch, WBS=152, t-rider.
// NEW vs R7: stg read via __builtin_nontemporal_load on a clang ext-vector
// f32x4 (HIP float4 is a struct the builtin rejects) — stg is a 72MB
// stream-once tensor; NT keeps it out of L2 so qtb (re-read 15x/panel) and
// xnb (re-read 5x) stay resident.
// ---------------------------------------------------------------------------
__global__ __launch_bounds__(256, 4) void score_k(const __bf16* __restrict__ qtb,
                                                  const float* __restrict__ cq,
                                                  const __bf16* __restrict__ xnb,
                                                  const float* __restrict__ stg,
                                                  __bf16* __restrict__ sag,
                                                  __bf16* __restrict__ xnT) {
    __shared__ unsigned short wb[64 * WBS];   // 19.5 KB (score) / 8.3 KB (t)
    int vb = blockIdx.x;
    int t = threadIdx.x;

    if (vb >= SCORE_VB) {
        // ---- transpose rider: xnb[b,j,d] -> xnT[b,d,j] ----
        int u = vb - SCORE_VB;
        int bb = u / 58, j0 = (u % 58) * 64;
        unsigned short (*tile)[65] = (unsigned short(*)[65])wb;
        const unsigned short* src = (const unsigned short*)xnb;
        unsigned short* dst = (unsigned short*)xnT;
#pragma unroll
        for (int i = 0; i < 16; ++i) {
            int f = t + 256 * i, jr = f >> 6, dc = f & 63;
            int j = j0 + jr;
            tile[jr][dc] = (j < TN) ? src[((size_t)bb * TN + j) * 64 + dc] : (unsigned short)0;
        }
        __syncthreads();
#pragma unroll
        for (int i = 0; i < 16; ++i) {
            int f = t + 256 * i, d = f >> 6, jj = f & 63;
            dst[((size_t)bb * 64 + d) * SSTR + j0 + jj] = tile[jj][d];
        }
        return;
    }

    int jb = vb % 29, nb = (vb / 29) % 5, bb = vb / 145;
    int n0 = nb * 64, j0 = jb * 128;
    int w = t >> 6, lane = t & 63;
    int m16 = lane & 15, q4 = lane >> 4;

    // ---- prefetch stg tiles (8 x f32x4, NT) + cq (4) into registers ----
    const float* stgb = stg + (size_t)bb * NN * TN;
    f32x4 sv[4][2];
    float cn[4];
#pragma unroll
    for (int nt = 0; nt < 4; ++nt) {
        int n = n0 + nt * 16 + m16;
        const float* srow = stgb + (size_t)min(n, NN - 1) * TN;
#pragma unroll
        for (int jj = 0; jj < 2; ++jj) {
            int jb2 = j0 + (w * 2 + jj) * 16 + q4 * 4;   // 4-aligned; TN is 4-aligned
            f32x4 s4 = {0.f, 0.f, 0.f, 0.f};
            if (jb2 < TN)
                s4 = __builtin_nontemporal_load(reinterpret_cast<const f32x4*>(srow + jb2));
            sv[nt][jj] = s4;
        }
        cn[nt] = (n < NN) ? cq[bb * NN + n] : 0.f;
    }

    // ---- A fragments: xnb rows j (2 jt tiles per wave) ----
    bf16x8 a[2][2];
#pragma unroll
    for (int jj = 0; jj < 2; ++jj) {
        const bf16x8* ap = (const bf16x8*)(xnb + ((size_t)bb * TN + j0 + (w * 2 + jj) * 16 + m16) * 64);
        a[jj][0] = ap[q4];
        a[jj][1] = ap[q4 + 4];
    }

    // ---- MFMA: C[j_local][n_local], 2 jt x 4 nt tiles per wave ----
    f32x4 acc[2][4];
#pragma unroll
    for (int nt = 0; nt < 4; ++nt) {
        const bf16x8* bp = (const bf16x8*)(qtb + ((size_t)bb * NN + n0 + nt * 16 + m16) * 64);
        bf16x8 b0 = bp[q4], b1 = bp[q4 + 4];
#pragma unroll
        for (int jj = 0; jj < 2; ++jj) {
            f32x4 c = {0.f, 0.f, 0.f, 0.f};
            c = __builtin_amdgcn_mfma_f32_16x16x32_bf16(a[jj][0], b0, c, 0, 0, 0);
            c = __builtin_amdgcn_mfma_f32_16x16x32_bf16(a[jj][1], b1, c, 0, 0, 0);
            acc[jj][nt] = c;
        }
    }

    // ---- epilogue: sigmoid(dg)*stg*scale from registers only ----
#pragma unroll
    for (int nt = 0; nt < 4; ++nt) {
#pragma unroll
        for (int jj = 0; jj < 2; ++jj) {
            int jb2 = j0 + (w * 2 + jj) * 16 + q4 * 4;
            u16x4 hw;
#pragma unroll
            for (int r = 0; r < 4; ++r) {
                float dg = (acc[jj][nt][r] + cn[nt]) * SCALE;
                float s  = 1.f / (1.f + __expf(-dg));
                float wv = (jb2 + r < TN) ? s * sv[nt][jj][r] * SCALE : 0.f;
                __bf16 wb16 = (__bf16)wv;
                hw[r] = *(unsigned short*)&wb16;
            }
            *(u16x4*)&wb[(nt * 16 + m16) * WBS + (w * 2 + jj) * 16 + q4 * 4] = hw;
        }
    }
    __syncthreads();

    // ---- coalesced b128 stores ----
#pragma unroll
    for (int i = 0; i < 4; ++i) {
        int chunk = t + i * 256;          // 0..1023
        int row = chunk >> 4, c8 = (chunk & 15) * 8;
        int n = n0 + row;
        if (n < NN) {
            u16x8 v = *(const u16x8*)&wb[row * WBS + c8];
            *(u16x8*)((unsigned short*)sag + (size_t)(bb * NN + n) * SST1 + j0 + c8) = v;
        }
    }
}

// ---------------------------------------------------------------------------
// Softmax+topk, one wave per row, zero LDS. Writes UNnormalized exp weights
// in place + per-row sum to rsum[]; pv divides in its epilogue.
// ---------------------------------------------------------------------------
__global__ __launch_bounds__(256) void smax_k(__bf16* __restrict__ sagB,
                                              const int* __restrict__ topk_p,
                                              float* __restrict__ rsum) {
    int t = threadIdx.x;
    int wid = t >> 6, lane = t & 63;
    int row = blockIdx.x * 4 + wid;
    if (row >= ROWSH) return;

    int topkv = *topk_p;
    bool selAll = (topkv <= 0);
    int kk = 0;
    if (!selAll) {
        kk = (topkv < 5) ? topkv * NN : topkv;
        if (kk > TN) kk = TN;
    }

    u16x8* src = (u16x8*)((unsigned short*)sagB + (size_t)row * SST1);
    u16x8 va[8];
#pragma unroll
    for (int ci = 0; ci < 8; ++ci) {
        int c = lane + (ci << 6);
        u16x8 v = {0, 0, 0, 0, 0, 0, 0, 0};
        if (c < 464) v = src[c];
        va[ci] = v;
    }
    // row max (values >= 0; bf16 bit order = value order; pads 0)
    int vmb = 0;
#pragma unroll
    for (int ci = 0; ci < 8; ++ci)
#pragma unroll
        for (int e = 0; e < 8; ++e) vmb = max(vmb, (int)va[ci][e]);
#pragma unroll
    for (int m = 32; m > 0; m >>= 1) vmb = max(vmb, __shfl_xor(vmb, m, 64));
    float vmax = __uint_as_float(((unsigned)vmb) << 16);

    // exact kk-th largest: smallest T with cnt(>T) < kk (ballot+popcount)
    unsigned thrb = 0;
    if (!selAll) {
        unsigned lo = 0, hi = (unsigned)vmb;
        while (lo < hi) {
            unsigned mid = (lo + hi) >> 1;
            int cnt = 0;
#pragma unroll
            for (int ci = 0; ci < 8; ++ci)
#pragma unroll
                for (int e = 0; e < 8; ++e)
                    cnt += (int)__popcll(__ballot((unsigned)va[ci][e] > mid));
            if (cnt < kk) hi = mid; else lo = mid + 1;
        }
        thrb = lo;
    }

    // exp over selected (store unnormalized exp as bf16)
    float local = 0.f;
#pragma unroll
    for (int ci = 0; ci < 8; ++ci) {
        int c = lane + (ci << 6);
        int nvv = (c < 460) ? 8 : ((c == 460) ? 4 : 0);
#pragma unroll
        for (int e = 0; e < 8; ++e) {
            unsigned u = va[ci][e];
            bool sel = selAll ? (e < nvv) : (u > thrb);
            float ev = sel ? __expf(__uint_as_float(u << 16) - vmax) : 0.f;
            local += ev;
            __bf16 eb = (__bf16)ev;
            va[ci][e] = *(unsigned short*)&eb;
        }
    }
    local = wred_sum(local);
    bool uni = !(local > 0.f);
    if (lane == 0) rsum[row] = uni ? (float)TN : local;

    if (uni) {
        __bf16 one = (__bf16)1.f, zero = (__bf16)0.f;
#pragma unroll
        for (int ci = 0; ci < 8; ++ci) {
            int c = lane + (ci << 6);
            if (c < 464) {
                int nvv = (c < 460) ? 8 : ((c == 460) ? 4 : 0);
                bf16x8 o;
#pragma unroll
                for (int e = 0; e < 8; ++e) o[e] = (e < nvv) ? one : zero;
                *(bf16x8*)&src[c] = o;
            }
        }
    } else {
#pragma unroll
        for (int ci = 0; ci < 8; ++ci) {
            int c = lane + (ci << 6);
            if (c < 464) src[c] = va[ci];
        }
    }
}

// ---------------------------------------------------------------------------
// PV GEMM, K-split 4 across blocks, XCD-swizzled (1280 = 8x160, bijective):
// all 20 n-blocks sharing one (bb,kq) xnT panel land on one XCD's L2.
// ---------------------------------------------------------------------------
__global__ __launch_bounds__(256) void pv_k(const __bf16* __restrict__ sagB,
                                            const __bf16* __restrict__ xnT,
                                            const float* __restrict__ y32,
                                            const float* __restrict__ rsum,
                                            float* __restrict__ hp) {
    int p = blockIdx.x + 20 * (blockIdx.y + 4 * blockIdx.z);   // 0..1279
    int l = (p & 7) * 160 + (p >> 3);
    int n0 = (l % 20) * 16;
    int kq = (l / 20) & 3;
    int bb = l / 80;
    int wid = threadIdx.x >> 6, lane = threadIdx.x & 63;
    int m16 = lane & 15, q4 = lane >> 4;

    int arow = min(n0 + m16, NN - 1);   // clamp: garbage rows masked at store
    const __bf16* ab  = sagB + (size_t)(bb * NN + arow) * SST1 + kq * KQ + q4 * 8;
    const __bf16* bbp = xnT + ((size_t)bb * 64 + wid * 16 + m16) * SSTR + kq * KQ + q4 * 8;

    f32x4 acc0 = {0.f, 0.f, 0.f, 0.f}, acc1 = {0.f, 0.f, 0.f, 0.f};
#pragma unroll 4
    for (int ks = 0; ks < 29; ++ks) {               // 29 * K32 = 928
        bf16x8 a = *(const bf16x8*)(ab + ks * 32);
        bf16x8 b = *(const bf16x8*)(bbp + ks * 32);
        if (ks & 1) acc1 = __builtin_amdgcn_mfma_f32_16x16x32_bf16(a, b, acc1, 0, 0, 0);
        else        acc0 = __builtin_amdgcn_mfma_f32_16x16x32_bf16(a, b, acc0, 0, 0, 0);
    }
    // C layout: row = q4*4+r (A-row = n), col = m16 (B-row = d within tile)
#pragma unroll
    for (int r = 0; r < 4; ++r) {
        int n = n0 + q4 * 4 + r;
        if (n < NN) {
            size_t o = (size_t)(bb * NN + n) * 64 + wid * 16 + m16;
            float inv = 1.f / rsum[bb * NN + n];
            float v = (acc0[r] + acc1[r]) * inv;
            if (kq == 0) v += y32[o];
            hp[(size_t)kq * HPS + o] = v;
        }
    }
}

// ---------------------------------------------------------------------------
// FFN via MFMA bf16: h = sum(hp[0..3]) -> LN -> @fc1^T+relu -> @fc2^T + h + b.
// hsum stashed in LDS during the LN pass.
// ---------------------------------------------------------------------------
__global__ __launch_bounds__(256) void ffn_k(const float* __restrict__ hp,
                                             const float* __restrict__ g,
                                             const float* __restrict__ bln,
                                             const __bf16* __restrict__ fc1b16,
                                             const float* __restrict__ fc1b,
                                             const __bf16* __restrict__ fc2b16,
                                             const float* __restrict__ fc2b,
                                             float* __restrict__ out) {
    __shared__ __bf16 zb[16 * 68];
    __shared__ __bf16 ab[16 * 264];
    __shared__ float hs[16][66];
    int t = threadIdx.x, r0 = blockIdx.x * 16;
    int wid = t >> 6, lane = t & 63;
    int m16 = lane & 15, q4 = lane >> 4;

#pragma unroll
    for (int q = 0; q < 4; ++q) {
        int rl = wid * 4 + q;
        size_t i = (size_t)(r0 + rl) * 64 + lane;
        float val = hp[i] + hp[HPS + i] + hp[2 * HPS + i] + hp[3 * HPS + i];
        hs[rl][lane] = val;
        float mu  = wred_sum(val) * (1.f / 64.f);
        float dv  = val - mu;
        float var = wred_sum(dv * dv) * (1.f / 64.f);
        zb[rl * 68 + lane] = (__bf16)(dv * rsqrtf(var + 1e-5f) * g[lane] + bln[lane]);
    }
    __syncthreads();

    bf16x8 a0 = *(const bf16x8*)&zb[m16 * 68 + q4 * 8];
    bf16x8 a1 = *(const bf16x8*)&zb[m16 * 68 + 32 + q4 * 8];
#pragma unroll
    for (int jt2 = 0; jt2 < 4; ++jt2) {
        int j0t = (wid * 4 + jt2) * 16;
        const __bf16* bp = fc1b16 + (size_t)(j0t + m16) * 64 + q4 * 8;
        f32x4 c = {0.f, 0.f, 0.f, 0.f};
        c = __builtin_amdgcn_mfma_f32_16x16x32_bf16(a0, *(const bf16x8*)bp, c, 0, 0, 0);
        c = __builtin_amdgcn_mfma_f32_16x16x32_bf16(a1, *(const bf16x8*)(bp + 32), c, 0, 0, 0);
        int j = j0t + m16;
        float bias = fc1b[j];
#pragma unroll
        for (int r = 0; r < 4; ++r)
            ab[(q4 * 4 + r) * 264 + j] = (__bf16)fmaxf(c[r] + bias, 0.f);
    }
    __syncthreads();

    f32x4 c2a = {0.f, 0.f, 0.f, 0.f}, c2b = {0.f, 0.f, 0.f, 0.f};
    const __bf16* b2p = fc2b16 + (size_t)(wid * 16 + m16) * 256 + q4 * 8;
#pragma unroll
    for (int k8 = 0; k8 < 8; k8 += 2) {
        bf16x8 aa0 = *(const bf16x8*)&ab[m16 * 264 + k8 * 32 + q4 * 8];
        bf16x8 aa1 = *(const bf16x8*)&ab[m16 * 264 + (k8 + 1) * 32 + q4 * 8];
        c2a = __builtin_amdgcn_mfma_f32_16x16x32_bf16(aa0, *(const bf16x8*)(b2p + k8 * 32), c2a, 0, 0, 0);
        c2b = __builtin_amdgcn_mfma_f32_16x16x32_bf16(aa1, *(const bf16x8*)(b2p + (k8 + 1) * 32), c2b, 0, 0, 0);
    }
    int d = wid * 16 + m16;
    float bias2 = fc2b[d];
#pragma unroll
    for (int r = 0; r < 4; ++r) {
        size_t row = (size_t)(r0 + q4 * 4 + r);
        size_t o = row * 64 + d;
        out[o] = hs[q4 * 4 + r][d] + c2a[r] + c2b[r] + bias2;
    }
}

extern "C" void kernel_launch(void* const* d_in, const int* in_sizes, int n_in,
                              void* d_out, int out_size, void* d_ws, size_t ws_size,
                              hipStream_t stream) {
    const float* x    = (const float*)d_in[0];
    const float* stg  = (const float*)d_in[1];
    const int*   topk = (const int*)d_in[2];
    const float* qw   = (const float*)d_in[3];
    const float* qb   = (const float*)d_in[4];
    const float* kw   = (const float*)d_in[5];
    const float* kb   = (const float*)d_in[6];
    const float* lng  = (const float*)d_in[7];
    const float* lnb  = (const float*)d_in[8];
    const float* flng = (const float*)d_in[9];
    const float* flnb = (const float*)d_in[10];
    const float* fc1w = (const float*)d_in[11];
    const float* fc1b = (const float*)d_in[12];
    const float* fc2w = (const float*)d_in[13];
    const float* fc2b = (const float*)d_in[14];
    float* out = (float*)d_out;

    float* ws = (float*)d_ws;
    __bf16* xnb = (__bf16*)ws;                 // ROWSX*64 bf16 = 1,886,208 f
    float* p1   = ws + 1886208;
    __bf16* xnT = (__bf16*)p1;                 // 16*64*3840 bf16 = 1,966,080 f
    float* p2   = p1 + 1966080;
    __bf16* qtb = (__bf16*)p2;                 // 4928*64 bf16 = 157,696 f
    float* y32  = p2 + 157696;                 // 314,368 f
    float* cq   = y32 + 314368;                // 4,928 f
    float* M    = cq + 4928;                   // 4,096
    float* b2   = M + 4096;                    // 64
    float* vv   = b2 + 64;                     // 64
    float* cc   = vv + 64;                     // 16
    __bf16* fc1b16 = (__bf16*)(cc + 16);       // 8,192 f
    __bf16* fc2b16 = (__bf16*)((float*)fc1b16 + 8192);  // 8,192 f
    __bf16* sag = (__bf16*)((float*)fc2b16 + 8192);     // ROWSH*3712 bf16 = 9,116,672 f
    float* hp   = (float*)sag + 9116672;       // 4*314,368 f (K-split partials)
    float* rsum = hp + 4 * HPS;                // 4,928 f

    prep_k<<<144 + (ROWSX + 3) / 4, 256, 0, stream>>>(qw, qb, kw, kb, fc1w, fc2w,
                                                      x, lng, lnb,
                                                      M, b2, vv, cc,
                                                      fc1b16, fc2b16, xnb, y32);
    qt_k<<<(ROWSH + 3) / 4, 256, 0, stream>>>(y32, M, b2, vv, cc, qtb, cq);
    score_k<<<SCORE_VB + 58 * BB, 256, 0, stream>>>(qtb, cq, xnb, stg, sag, xnT);
    smax_k<<<(ROWSH + 3) / 4, 256, 0, stream>>>(sag, topk, rsum);
    pv_k<<<dim3((NN + 15) / 16, 4, BB), 256, 0, stream>>>(sag, xnT, y32, rsum, hp);
    ffn_k<<<ROWSH / 16, 256, 0, stream>>>(hp, flng, flnb, fc1b16, fc1b, fc2b16, fc2b, out);
}

// Round 12
// 242.178 us; speedup vs baseline: 1.0347x; 1.0333x over previous
//
#include <hip/hip_runtime.h>

typedef __bf16 bf16x8 __attribute__((ext_vector_type(8)));
typedef float  f32x4  __attribute__((ext_vector_type(4)));
typedef unsigned short u16x8 __attribute__((ext_vector_type(8)));
typedef unsigned short u16x4 __attribute__((ext_vector_type(4)));

// Problem constants
constexpr int BB    = 16;
constexpr int TT    = 12;
constexpr int NN    = 307;
constexpr int TN    = TT * NN;        // 3684
constexpr int ROWSX = BB * TT * NN;   // 58944
constexpr int ROWSH = BB * NN;        // 4912
constexpr int SST1  = 3712;           // sag row stride (464 x b128 chunks)
constexpr int SSTR  = 3840;           // xnT row stride
constexpr int HPS   = ROWSH * 64;     // hp slab stride (314368 floats)
constexpr int KQ    = 928;            // pv K-split chunk (3712/4)
constexpr int WBS   = 152;            // score LDS stride: 76 dw = 12 mod 32 -> 2-way max
constexpr int SCORE_VB = 145 * BB;    // 29 j-blk x 5 n-blk x 16 = 2320
constexpr float SCALE = 0.125f;

__device__ __forceinline__ float wred_sum(float v) {
#pragma unroll
    for (int m = 32; m > 0; m >>= 1) v += __shfl_xor(v, m, 64);
    return v;
}

// ---------------------------------------------------------------------------
// prep_k: grid-specialized merge of fold (16 blk) + wconv (128 blk) + ln
// (14736 blk). All three depend only on kernel inputs.
// ---------------------------------------------------------------------------
__global__ __launch_bounds__(256) void prep_k(const float* __restrict__ qw,
                                              const float* __restrict__ qb,
                                              const float* __restrict__ kw,
                                              const float* __restrict__ kb,
                                              const float* __restrict__ fc1w,
                                              const float* __restrict__ fc2w,
                                              const float* __restrict__ x,
                                              const float* __restrict__ g,
                                              const float* __restrict__ b,
                                              float* __restrict__ M,
                                              float* __restrict__ b2,
                                              float* __restrict__ vv,
                                              float* __restrict__ cc,
                                              __bf16* __restrict__ fc1b16,
                                              __bf16* __restrict__ fc2b16,
                                              __bf16* __restrict__ xnb,
                                              float* __restrict__ y32) {
    int bx = blockIdx.x, t = threadIdx.x;
    int w = t >> 6, lane = t & 63;
    if (bx < 16) {
        // ---- fold: dg = q.k = qt.x_ + c ----
        int e = bx * 4 + w, d = lane;
        float acc = 0.f;
        for (int dp = 0; dp < 64; ++dp) acc += qw[dp * 64 + e] * kw[dp * 64 + d];
        M[e * 64 + d] = acc;
        float vp = wred_sum(qw[d * 64 + e] * kb[d]);
        if (lane == 0) vv[e] = vp;
        if (e == 0) {
            float bv = 0.f;
            for (int dp = 0; dp < 64; ++dp) bv += qb[dp] * kw[dp * 64 + d];
            b2[d] = bv;
            float cp = wred_sum(qb[d] * kb[d]);
            if (d == 0) *cc = cp;
        }
    } else if (bx < 144) {
        // ---- wconv: fc1w/fc2w fp32 -> bf16 ----
        int i = (bx - 16) * 256 + t;
        if (i < 16384) fc1b16[i] = (__bf16)fc1w[i];
        else fc2b16[i - 16384] = (__bf16)fc2w[i - 16384];
    } else {
        // ---- ln: 1 row/wave ----
        int r = (bx - 144) * 4 + w;
        if (r >= ROWSX) return;
        float val = x[r * 64 + lane];
        float mu  = wred_sum(val) * (1.f / 64.f);
        float dv  = val - mu;
        float var = wred_sum(dv * dv) * (1.f / 64.f);
        float xv  = dv * rsqrtf(var + 1e-5f) * g[lane] + b[lane];
        xnb[(size_t)r * 64 + lane] = (__bf16)xv;
        int tt = (r / NN) % TT;
        if (tt == TT - 1) {
            int bbv = r / (NN * TT), n = r % NN;
            y32[(bbv * NN + n) * 64 + lane] = xv;
        }
    }
}

// ---------------------------------------------------------------------------
// qt[row] = y_ @ M + b2 (bf16);  cq[row] = y_.v + cc
// ---------------------------------------------------------------------------
__global__ __launch_bounds__(256) void qt_k(const float* __restrict__ y32,
                                            const float* __restrict__ M,
                                            const float* __restrict__ b2,
                                            const float* __restrict__ vv,
                                            const float* __restrict__ ccp,
                                            __bf16* __restrict__ qtb,
                                            float* __restrict__ cq) {
    int w = threadIdx.x >> 6, l = threadIdx.x & 63;
    int rr = blockIdx.x * 4 + w;
    if (rr >= ROWSH) return;
    float y = y32[rr * 64 + l];
    float acc = b2[l];
#pragma unroll
    for (int e = 0; e < 64; ++e) acc += __shfl(y, e, 64) * M[e * 64 + l];
    qtb[(size_t)rr * 64 + l] = (__bf16)acc;
    float cp = wred_sum(y * vv[l]);
    if (l == 0) cq[rr] = cp + *ccp;
}

// ---------------------------------------------------------------------------
// score_k (R7 config — best measured across R8 occupancy-2x, R9 tile
// reshape, R11 nontemporal: all regressed; reverted). 64n x 128j tiles,
// register-prefetch stg+cq before MFMA, WBS=152 (2-way max scatter),
// coalesced b128 stores, t-rider off the critical path.
// ---------------------------------------------------------------------------
__global__ __launch_bounds__(256, 4) void score_k(const __bf16* __restrict__ qtb,
                                                  const float* __restrict__ cq,
                                                  const __bf16* __restrict__ xnb,
                                                  const float* __restrict__ stg,
                                                  __bf16* __restrict__ sag,
                                                  __bf16* __restrict__ xnT) {
    __shared__ unsigned short wb[64 * WBS];   // 19.5 KB (score) / 8.3 KB (t)
    int vb = blockIdx.x;
    int t = threadIdx.x;

    if (vb >= SCORE_VB) {
        // ---- transpose rider: xnb[b,j,d] -> xnT[b,d,j] ----
        int u = vb - SCORE_VB;
        int bb = u / 58, j0 = (u % 58) * 64;
        unsigned short (*tile)[65] = (unsigned short(*)[65])wb;
        const unsigned short* src = (const unsigned short*)xnb;
        unsigned short* dst = (unsigned short*)xnT;
#pragma unroll
        for (int i = 0; i < 16; ++i) {
            int f = t + 256 * i, jr = f >> 6, dc = f & 63;
            int j = j0 + jr;
            tile[jr][dc] = (j < TN) ? src[((size_t)bb * TN + j) * 64 + dc] : (unsigned short)0;
        }
        __syncthreads();
#pragma unroll
        for (int i = 0; i < 16; ++i) {
            int f = t + 256 * i, d = f >> 6, jj = f & 63;
            dst[((size_t)bb * 64 + d) * SSTR + j0 + jj] = tile[jj][d];
        }
        return;
    }

    int jb = vb % 29, nb = (vb / 29) % 5, bb = vb / 145;
    int n0 = nb * 64, j0 = jb * 128;
    int w = t >> 6, lane = t & 63;
    int m16 = lane & 15, q4 = lane >> 4;

    // ---- prefetch stg tiles (8 x f32x4) + cq (4) into registers ----
    const float* stgb = stg + (size_t)bb * NN * TN;
    f32x4 sv[4][2];
    float cn[4];
#pragma unroll
    for (int nt = 0; nt < 4; ++nt) {
        int n = n0 + nt * 16 + m16;
        const float* srow = stgb + (size_t)min(n, NN - 1) * TN;
#pragma unroll
        for (int jj = 0; jj < 2; ++jj) {
            int jb2 = j0 + (w * 2 + jj) * 16 + q4 * 4;   // 4-aligned; TN is 4-aligned
            f32x4 s4 = {0.f, 0.f, 0.f, 0.f};
            if (jb2 < TN) s4 = *reinterpret_cast<const f32x4*>(srow + jb2);
            sv[nt][jj] = s4;
        }
        cn[nt] = (n < NN) ? cq[bb * NN + n] : 0.f;
    }

    // ---- A fragments: xnb rows j (2 jt tiles per wave) ----
    bf16x8 a[2][2];
#pragma unroll
    for (int jj = 0; jj < 2; ++jj) {
        const bf16x8* ap = (const bf16x8*)(xnb + ((size_t)bb * TN + j0 + (w * 2 + jj) * 16 + m16) * 64);
        a[jj][0] = ap[q4];
        a[jj][1] = ap[q4 + 4];
    }

    // ---- MFMA: C[j_local][n_local], 2 jt x 4 nt tiles per wave ----
    f32x4 acc[2][4];
#pragma unroll
    for (int nt = 0; nt < 4; ++nt) {
        const bf16x8* bp = (const bf16x8*)(qtb + ((size_t)bb * NN + n0 + nt * 16 + m16) * 64);
        bf16x8 b0 = bp[q4], b1 = bp[q4 + 4];
#pragma unroll
        for (int jj = 0; jj < 2; ++jj) {
            f32x4 c = {0.f, 0.f, 0.f, 0.f};
            c = __builtin_amdgcn_mfma_f32_16x16x32_bf16(a[jj][0], b0, c, 0, 0, 0);
            c = __builtin_amdgcn_mfma_f32_16x16x32_bf16(a[jj][1], b1, c, 0, 0, 0);
            acc[jj][nt] = c;
        }
    }

    // ---- epilogue: sigmoid(dg)*stg*scale from registers only ----
#pragma unroll
    for (int nt = 0; nt < 4; ++nt) {
#pragma unroll
        for (int jj = 0; jj < 2; ++jj) {
            int jb2 = j0 + (w * 2 + jj) * 16 + q4 * 4;
            u16x4 hw;
#pragma unroll
            for (int r = 0; r < 4; ++r) {
                float dg = (acc[jj][nt][r] + cn[nt]) * SCALE;
                float s  = 1.f / (1.f + __expf(-dg));
                float wv = (jb2 + r < TN) ? s * sv[nt][jj][r] * SCALE : 0.f;
                __bf16 wb16 = (__bf16)wv;
                hw[r] = *(unsigned short*)&wb16;
            }
            *(u16x4*)&wb[(nt * 16 + m16) * WBS + (w * 2 + jj) * 16 + q4 * 4] = hw;
        }
    }
    __syncthreads();

    // ---- coalesced b128 stores ----
#pragma unroll
    for (int i = 0; i < 4; ++i) {
        int chunk = t + i * 256;          // 0..1023
        int row = chunk >> 4, c8 = (chunk & 15) * 8;
        int n = n0 + row;
        if (n < NN) {
            u16x8 v = *(const u16x8*)&wb[row * WBS + c8];
            *(u16x8*)((unsigned short*)sag + (size_t)(bb * NN + n) * SST1 + j0 + c8) = v;
        }
    }
}

// ---------------------------------------------------------------------------
// Softmax+topk, one wave per row, zero LDS. Writes UNnormalized exp weights
// in place + per-row sum to rsum[]; pv divides in its epilogue.
// ---------------------------------------------------------------------------
__global__ __launch_bounds__(256) void smax_k(__bf16* __restrict__ sagB,
                                              const int* __restrict__ topk_p,
                                              float* __restrict__ rsum) {
    int t = threadIdx.x;
    int wid = t >> 6, lane = t & 63;
    int row = blockIdx.x * 4 + wid;
    if (row >= ROWSH) return;

    int topkv = *topk_p;
    bool selAll = (topkv <= 0);
    int kk = 0;
    if (!selAll) {
        kk = (topkv < 5) ? topkv * NN : topkv;
        if (kk > TN) kk = TN;
    }

    u16x8* src = (u16x8*)((unsigned short*)sagB + (size_t)row * SST1);
    u16x8 va[8];
#pragma unroll
    for (int ci = 0; ci < 8; ++ci) {
        int c = lane + (ci << 6);
        u16x8 v = {0, 0, 0, 0, 0, 0, 0, 0};
        if (c < 464) v = src[c];
        va[ci] = v;
    }
    // row max (values >= 0; bf16 bit order = value order; pads 0)
    int vmb = 0;
#pragma unroll
    for (int ci = 0; ci < 8; ++ci)
#pragma unroll
        for (int e = 0; e < 8; ++e) vmb = max(vmb, (int)va[ci][e]);
#pragma unroll
    for (int m = 32; m > 0; m >>= 1) vmb = max(vmb, __shfl_xor(vmb, m, 64));
    float vmax = __uint_as_float(((unsigned)vmb) << 16);

    // exact kk-th largest: smallest T with cnt(>T) < kk (ballot+popcount)
    unsigned thrb = 0;
    if (!selAll) {
        unsigned lo = 0, hi = (unsigned)vmb;
        while (lo < hi) {
            unsigned mid = (lo + hi) >> 1;
            int cnt = 0;
#pragma unroll
            for (int ci = 0; ci < 8; ++ci)
#pragma unroll
                for (int e = 0; e < 8; ++e)
                    cnt += (int)__popcll(__ballot((unsigned)va[ci][e] > mid));
            if (cnt < kk) hi = mid; else lo = mid + 1;
        }
        thrb = lo;
    }

    // exp over selected (store unnormalized exp as bf16)
    float local = 0.f;
#pragma unroll
    for (int ci = 0; ci < 8; ++ci) {
        int c = lane + (ci << 6);
        int nvv = (c < 460) ? 8 : ((c == 460) ? 4 : 0);
#pragma unroll
        for (int e = 0; e < 8; ++e) {
            unsigned u = va[ci][e];
            bool sel = selAll ? (e < nvv) : (u > thrb);
            float ev = sel ? __expf(__uint_as_float(u << 16) - vmax) : 0.f;
            local += ev;
            __bf16 eb = (__bf16)ev;
            va[ci][e] = *(unsigned short*)&eb;
        }
    }
    local = wred_sum(local);
    bool uni = !(local > 0.f);
    if (lane == 0) rsum[row] = uni ? (float)TN : local;

    if (uni) {
        __bf16 one = (__bf16)1.f, zero = (__bf16)0.f;
#pragma unroll
        for (int ci = 0; ci < 8; ++ci) {
            int c = lane + (ci << 6);
            if (c < 464) {
                int nvv = (c < 460) ? 8 : ((c == 460) ? 4 : 0);
                bf16x8 o;
#pragma unroll
                for (int e = 0; e < 8; ++e) o[e] = (e < nvv) ? one : zero;
                *(bf16x8*)&src[c] = o;
            }
        }
    } else {
#pragma unroll
        for (int ci = 0; ci < 8; ++ci) {
            int c = lane + (ci << 6);
            if (c < 464) src[c] = va[ci];
        }
    }
}

// ---------------------------------------------------------------------------
// PV GEMM, K-split 4 across blocks, XCD-swizzled (1280 = 8x160, bijective):
// all 20 n-blocks sharing one (bb,kq) xnT panel land on one XCD's L2.
// ---------------------------------------------------------------------------
__global__ __launch_bounds__(256) void pv_k(const __bf16* __restrict__ sagB,
                                            const __bf16* __restrict__ xnT,
                                            const float* __restrict__ y32,
                                            const float* __restrict__ rsum,
                                            float* __restrict__ hp) {
    int p = blockIdx.x + 20 * (blockIdx.y + 4 * blockIdx.z);   // 0..1279
    int l = (p & 7) * 160 + (p >> 3);
    int n0 = (l % 20) * 16;
    int kq = (l / 20) & 3;
    int bb = l / 80;
    int wid = threadIdx.x >> 6, lane = threadIdx.x & 63;
    int m16 = lane & 15, q4 = lane >> 4;

    int arow = min(n0 + m16, NN - 1);   // clamp: garbage rows masked at store
    const __bf16* ab  = sagB + (size_t)(bb * NN + arow) * SST1 + kq * KQ + q4 * 8;
    const __bf16* bbp = xnT + ((size_t)bb * 64 + wid * 16 + m16) * SSTR + kq * KQ + q4 * 8;

    f32x4 acc0 = {0.f, 0.f, 0.f, 0.f}, acc1 = {0.f, 0.f, 0.f, 0.f};
#pragma unroll 4
    for (int ks = 0; ks < 29; ++ks) {               // 29 * K32 = 928
        bf16x8 a = *(const bf16x8*)(ab + ks * 32);
        bf16x8 b = *(const bf16x8*)(bbp + ks * 32);
        if (ks & 1) acc1 = __builtin_amdgcn_mfma_f32_16x16x32_bf16(a, b, acc1, 0, 0, 0);
        else        acc0 = __builtin_amdgcn_mfma_f32_16x16x32_bf16(a, b, acc0, 0, 0, 0);
    }
    // C layout: row = q4*4+r (A-row = n), col = m16 (B-row = d within tile)
#pragma unroll
    for (int r = 0; r < 4; ++r) {
        int n = n0 + q4 * 4 + r;
        if (n < NN) {
            size_t o = (size_t)(bb * NN + n) * 64 + wid * 16 + m16;
            float inv = 1.f / rsum[bb * NN + n];
            float v = (acc0[r] + acc1[r]) * inv;
            if (kq == 0) v += y32[o];
            hp[(size_t)kq * HPS + o] = v;
        }
    }
}

// ---------------------------------------------------------------------------
// FFN via MFMA bf16: h = sum(hp[0..3]) -> LN -> @fc1^T+relu -> @fc2^T + h + b.
// hsum stashed in LDS during the LN pass.
// ---------------------------------------------------------------------------
__global__ __launch_bounds__(256) void ffn_k(const float* __restrict__ hp,
                                             const float* __restrict__ g,
                                             const float* __restrict__ bln,
                                             const __bf16* __restrict__ fc1b16,
                                             const float* __restrict__ fc1b,
                                             const __bf16* __restrict__ fc2b16,
                                             const float* __restrict__ fc2b,
                                             float* __restrict__ out) {
    __shared__ __bf16 zb[16 * 68];
    __shared__ __bf16 ab[16 * 264];
    __shared__ float hs[16][66];
    int t = threadIdx.x, r0 = blockIdx.x * 16;
    int wid = t >> 6, lane = t & 63;
    int m16 = lane & 15, q4 = lane >> 4;

#pragma unroll
    for (int q = 0; q < 4; ++q) {
        int rl = wid * 4 + q;
        size_t i = (size_t)(r0 + rl) * 64 + lane;
        float val = hp[i] + hp[HPS + i] + hp[2 * HPS + i] + hp[3 * HPS + i];
        hs[rl][lane] = val;
        float mu  = wred_sum(val) * (1.f / 64.f);
        float dv  = val - mu;
        float var = wred_sum(dv * dv) * (1.f / 64.f);
        zb[rl * 68 + lane] = (__bf16)(dv * rsqrtf(var + 1e-5f) * g[lane] + bln[lane]);
    }
    __syncthreads();

    bf16x8 a0 = *(const bf16x8*)&zb[m16 * 68 + q4 * 8];
    bf16x8 a1 = *(const bf16x8*)&zb[m16 * 68 + 32 + q4 * 8];
#pragma unroll
    for (int jt2 = 0; jt2 < 4; ++jt2) {
        int j0t = (wid * 4 + jt2) * 16;
        const __bf16* bp = fc1b16 + (size_t)(j0t + m16) * 64 + q4 * 8;
        f32x4 c = {0.f, 0.f, 0.f, 0.f};
        c = __builtin_amdgcn_mfma_f32_16x16x32_bf16(a0, *(const bf16x8*)bp, c, 0, 0, 0);
        c = __builtin_amdgcn_mfma_f32_16x16x32_bf16(a1, *(const bf16x8*)(bp + 32), c, 0, 0, 0);
        int j = j0t + m16;
        float bias = fc1b[j];
#pragma unroll
        for (int r = 0; r < 4; ++r)
            ab[(q4 * 4 + r) * 264 + j] = (__bf16)fmaxf(c[r] + bias, 0.f);
    }
    __syncthreads();

    f32x4 c2a = {0.f, 0.f, 0.f, 0.f}, c2b = {0.f, 0.f, 0.f, 0.f};
    const __bf16* b2p = fc2b16 + (size_t)(wid * 16 + m16) * 256 + q4 * 8;
#pragma unroll
    for (int k8 = 0; k8 < 8; k8 += 2) {
        bf16x8 aa0 = *(const bf16x8*)&ab[m16 * 264 + k8 * 32 + q4 * 8];
        bf16x8 aa1 = *(const bf16x8*)&ab[m16 * 264 + (k8 + 1) * 32 + q4 * 8];
        c2a = __builtin_amdgcn_mfma_f32_16x16x32_bf16(aa0, *(const bf16x8*)(b2p + k8 * 32), c2a, 0, 0, 0);
        c2b = __builtin_amdgcn_mfma_f32_16x16x32_bf16(aa1, *(const bf16x8*)(b2p + (k8 + 1) * 32), c2b, 0, 0, 0);
    }
    int d = wid * 16 + m16;
    float bias2 = fc2b[d];
#pragma unroll
    for (int r = 0; r < 4; ++r) {
        size_t row = (size_t)(r0 + q4 * 4 + r);
        size_t o = row * 64 + d;
        out[o] = hs[q4 * 4 + r][d] + c2a[r] + c2b[r] + bias2;
    }
}

extern "C" void kernel_launch(void* const* d_in, const int* in_sizes, int n_in,
                              void* d_out, int out_size, void* d_ws, size_t ws_size,
                              hipStream_t stream) {
    const float* x    = (const float*)d_in[0];
    const float* stg  = (const float*)d_in[1];
    const int*   topk = (const int*)d_in[2];
    const float* qw   = (const float*)d_in[3];
    const float* qb   = (const float*)d_in[4];
    const float* kw   = (const float*)d_in[5];
    const float* kb   = (const float*)d_in[6];
    const float* lng  = (const float*)d_in[7];
    const float* lnb  = (const float*)d_in[8];
    const float* flng = (const float*)d_in[9];
    const float* flnb = (const float*)d_in[10];
    const float* fc1w = (const float*)d_in[11];
    const float* fc1b = (const float*)d_in[12];
    const float* fc2w = (const float*)d_in[13];
    const float* fc2b = (const float*)d_in[14];
    float* out = (float*)d_out;

    float* ws = (float*)d_ws;
    __bf16* xnb = (__bf16*)ws;                 // ROWSX*64 bf16 = 1,886,208 f
    float* p1   = ws + 1886208;
    __bf16* xnT = (__bf16*)p1;                 // 16*64*3840 bf16 = 1,966,080 f
    float* p2   = p1 + 1966080;
    __bf16* qtb = (__bf16*)p2;                 // 4928*64 bf16 = 157,696 f
    float* y32  = p2 + 157696;                 // 314,368 f
    float* cq   = y32 + 314368;                // 4,928 f
    float* M    = cq + 4928;                   // 4,096
    float* b2   = M + 4096;                    // 64
    float* vv   = b2 + 64;                     // 64
    float* cc   = vv + 64;                     // 16
    __bf16* fc1b16 = (__bf16*)(cc + 16);       // 8,192 f
    __bf16* fc2b16 = (__bf16*)((float*)fc1b16 + 8192);  // 8,192 f
    __bf16* sag = (__bf16*)((float*)fc2b16 + 8192);     // ROWSH*3712 bf16 = 9,116,672 f
    float* hp   = (float*)sag + 9116672;       // 4*314,368 f (K-split partials)
    float* rsum = hp + 4 * HPS;                // 4,928 f

    prep_k<<<144 + (ROWSX + 3) / 4, 256, 0, stream>>>(qw, qb, kw, kb, fc1w, fc2w,
                                                      x, lng, lnb,
                                                      M, b2, vv, cc,
                                                      fc1b16, fc2b16, xnb, y32);
    qt_k<<<(ROWSH + 3) / 4, 256, 0, stream>>>(y32, M, b2, vv, cc, qtb, cq);
    score_k<<<SCORE_VB + 58 * BB, 256, 0, stream>>>(qtb, cq, xnb, stg, sag, xnT);
    smax_k<<<(ROWSH + 3) / 4, 256, 0, stream>>>(sag, topk, rsum);
    pv_k<<<dim3((NN + 15) / 16, 4, BB), 256, 0, stream>>>(sag, xnT, y32, rsum, hp);
    ffn_k<<<ROWSH / 16, 256, 0, stream>>>(hp, flng, flnb, fc1b16, fc1b, fc2b16, fc2b, out);
}